// Round 11
// baseline (606.717 us; speedup 1.0000x reference)
//
#include <hip/hip_runtime.h>

#define EXP 8
#define DM 1024
#define DH 4096
#define NT 16384

typedef __attribute__((ext_vector_type(8))) short bf16x8;
typedef __attribute__((ext_vector_type(4))) float f32x4;

static __device__ __forceinline__ unsigned short f2bf(float f) {
  unsigned int u = __float_as_uint(f);
  u = u + 0x7FFFu + ((u >> 16) & 1u);
  return (unsigned short)(u >> 16);
}

static __device__ __forceinline__ void gload_lds16(const void* g, void* l) {
  __builtin_amdgcn_global_load_lds((const __attribute__((address_space(1))) void*)g,
                                   (__attribute__((address_space(3))) void*)l, 16, 0, 0);
}

// r3 swizzle: 16B-chunk index XOR (row&7), [*][64] bf16 tiles (0 conflicts)
static __device__ __forceinline__ int swz_idx(int r, int kk) {
  return r * 64 + (((kk >> 3) ^ (r & 7)) << 3);
}

// ---- X fp32 -> bf16 (same layout) ----
__global__ void cvt_bf16_k(const float* __restrict__ in, unsigned short* __restrict__ out,
                           long n4) {
  long i = (long)blockIdx.x * blockDim.x + threadIdx.x;
  const long stride = (long)gridDim.x * blockDim.x;
  for (; i < n4; i += stride) {
    const float4 v = ((const float4*)in)[i];
    ushort4 o;
    o.x = f2bf(v.x); o.y = f2bf(v.y); o.z = f2bf(v.z); o.w = f2bf(v.w);
    ((ushort4*)out)[i] = o;
  }
}

// ---- [B][K][N] fp32 -> [B][N][K] bf16, 64x64 tile, vectorized both sides ----
// reads float4 (256B/16-lane row), writes ushort4 (128B/16-lane row).
// tile[64][65]: both phases 2-way bank aliasing (free, m136).
// z = m*8 + e selects matrix (srcA/srcB) and expert.
__global__ void transpose_cvt64(const float* __restrict__ srcA, const float* __restrict__ srcB,
                                unsigned short* __restrict__ dstA,
                                unsigned short* __restrict__ dstB, int K, int N) {
  __shared__ float tile[64][65];
  const int t = threadIdx.x;
  const int tx = t & 15, ty = t >> 4;
  const int n0 = blockIdx.x * 64, k0 = blockIdx.y * 64;
  const int z = blockIdx.z;
  const float* src = (z >> 3 ? srcB : srcA) + (size_t)(z & 7) * K * N;
  unsigned short* dst = (z >> 3 ? dstB : dstA) + (size_t)(z & 7) * K * N;
#pragma unroll
  for (int i = 0; i < 64; i += 16) {
    const float4 v = *(const float4*)&src[(size_t)(k0 + ty + i) * N + n0 + tx * 4];
    tile[ty + i][tx * 4 + 0] = v.x;
    tile[ty + i][tx * 4 + 1] = v.y;
    tile[ty + i][tx * 4 + 2] = v.z;
    tile[ty + i][tx * 4 + 3] = v.w;
  }
  __syncthreads();
#pragma unroll
  for (int i = 0; i < 64; i += 16) {
    ushort4 o;
    o.x = f2bf(tile[tx * 4 + 0][ty + i]);
    o.y = f2bf(tile[tx * 4 + 1][ty + i]);
    o.z = f2bf(tile[tx * 4 + 2][ty + i]);
    o.w = f2bf(tile[tx * 4 + 3][ty + i]);
    *(ushort4*)&dst[(size_t)(n0 + ty + i) * K + k0 + tx * 4] = o;
  }
}

// ============================================================================
// GEMM1 = round-3 structure (measured best for K=1024 dual-B: 331 us, 37%).
// + T1 XCD-chunked remap: 4096 blocks, XCD k gets bids [512k,512k+512) ->
// mblk [16k,16k+16) = EXACTLY expert k -> weight panels never cross XCDs.
// ============================================================================
__global__ __launch_bounds__(256, 2) void gemm1(
    const unsigned short* __restrict__ Xb,
    const unsigned short* __restrict__ WgT,
    const unsigned short* __restrict__ WlT,
    const float* __restrict__ b_lin,
    unsigned short* __restrict__ Hb) {
  __shared__ unsigned short sA[128 * 64];
  __shared__ unsigned short sBg[128 * 64];
  __shared__ unsigned short sBl[128 * 64];

  const int t = threadIdx.x;
  const int bid = blockIdx.x + (int)gridDim.x * blockIdx.y;  // 4096 blocks
  const int nb = (bid & 7) * 512 + (bid >> 3);               // bijective (4096%8==0)
  const int nblk = nb & 31, mblk = nb >> 5;
  const int e = mblk >> 4;
  const int m0 = mblk * 128, n0 = nblk * 128;

  const int lane = t & 63;
  const int wave = t >> 6;
  const int wr = wave >> 1, wc = wave & 1;
  const int lrow = lane & 15;
  const int lk8 = (lane >> 4) * 8;

  const int srow = t >> 3;
  const int schunk = t & 7;
  const int ssw = ((schunk ^ (srow & 7)) << 3);

  const unsigned short* gA = Xb + (size_t)m0 * DM + ssw;
  const unsigned short* gG = WgT + (size_t)e * DH * DM + (size_t)n0 * DM + ssw;
  const unsigned short* gL = WlT + (size_t)e * DH * DM + (size_t)n0 * DM + ssw;

  f32x4 accg[4][4], accl[4][4];
#pragma unroll
  for (int i = 0; i < 4; i++)
#pragma unroll
    for (int j = 0; j < 4; j++) { accg[i][j] = 0.0f; accl[i][j] = 0.0f; }

  for (int kt = 0; kt < DM / 64; ++kt) {
    const int k0 = kt * 64;
#pragma unroll
    for (int c = 0; c < 4; c++) {
      const int row = c * 32 + srow;
      gload_lds16(gA + (size_t)row * DM + k0, (char*)sA + row * 128 + schunk * 16);
      gload_lds16(gG + (size_t)row * DM + k0, (char*)sBg + row * 128 + schunk * 16);
      gload_lds16(gL + (size_t)row * DM + k0, (char*)sBl + row * 128 + schunk * 16);
    }
    __syncthreads();
#pragma unroll
    for (int ks = 0; ks < 2; ks++) {
      const int kk = ks * 32 + lk8;
      bf16x8 af[4], bg[4], bl[4];
#pragma unroll
      for (int i = 0; i < 4; i++)
        af[i] = *(const bf16x8*)&sA[swz_idx(wr * 64 + i * 16 + lrow, kk)];
#pragma unroll
      for (int j = 0; j < 4; j++) {
        bg[j] = *(const bf16x8*)&sBg[swz_idx(wc * 64 + j * 16 + lrow, kk)];
        bl[j] = *(const bf16x8*)&sBl[swz_idx(wc * 64 + j * 16 + lrow, kk)];
      }
#pragma unroll
      for (int i = 0; i < 4; i++)
#pragma unroll
        for (int j = 0; j < 4; j++) {
          accg[i][j] = __builtin_amdgcn_mfma_f32_16x16x32_bf16(af[i], bg[j], accg[i][j], 0, 0, 0);
          accl[i][j] = __builtin_amdgcn_mfma_f32_16x16x32_bf16(af[i], bl[j], accl[i][j], 0, 0, 0);
        }
    }
    __syncthreads();
  }

  const float* bl_p = b_lin + (size_t)e * DH;
  const int r0 = (lane >> 4) * 4;
#pragma unroll
  for (int i = 0; i < 4; i++) {
    const int grow = m0 + wr * 64 + i * 16 + r0;
#pragma unroll
    for (int j = 0; j < 4; j++) {
      const int gcol = n0 + wc * 64 + j * 16 + lrow;
      const float bias = bl_p[gcol];
#pragma unroll
      for (int r = 0; r < 4; r++) {
        const float g = accg[i][j][r];
        const float li = accl[i][j][r] + bias;
        const float u = 0.7978845608028654f * (g + 0.044715f * g * g * g);
        const float th = 1.0f - 2.0f / (1.0f + __expf(2.0f * u));
        const float h = 0.5f * g * (1.0f + th) * li;
        Hb[(size_t)(grow + r) * DH + gcol] = f2bf(h);
      }
    }
  }
}

// ============================================================================
// GEMM2 = round-9 8-phase (measured ~120 us).  + T1 remap: 256 blocks, XCD k
// gets mblk [8k,8k+8) = exactly expert k.
// ============================================================================

#define LDSA(row, chunk) lds[sb + (row) * 64 + ((((chunk) ^ ((row) & 7))) << 3)]
#define LDSB(row, chunk) lds[sb + 16384 + (row) * 64 + ((((chunk) ^ ((row) & 7))) << 3)]

#define RD_A(mh)                                                                   \
  _Pragma("unroll") for (int i = 0; i < 4; i++) _Pragma("unroll") for (int ks = 0; \
                                                                       ks < 2;    \
                                                                       ks++)      \
      fa[i][ks] = *(const bf16x8*)&LDSA(wr * 128 + (mh) * 64 + i * 16 + lrow, ks * 4 + khi);

#define RD_B(dst, jb)                                                              \
  _Pragma("unroll") for (int j = 0; j < 2; j++) _Pragma("unroll") for (int ks = 0; \
                                                                       ks < 2;    \
                                                                       ks++)      \
      dst[j][ks] = *(const bf16x8*)&LDSB(wc * 64 + ((jb) + j) * 16 + lrow, ks * 4 + khi);

#define MFMA16(mi, jb, fb)                                                        \
  __builtin_amdgcn_s_setprio(1);                                                  \
  _Pragma("unroll") for (int i = 0; i < 4; i++) _Pragma("unroll") for (int j = 0; \
                                                                       j < 2;    \
                                                                       j++)      \
      _Pragma("unroll") for (int ks = 0; ks < 2; ks++) acc[(mi) + i][(jb) + j] =  \
          __builtin_amdgcn_mfma_f32_16x16x32_bf16(fa[i][ks], fb[j][ks],           \
                                                  acc[(mi) + i][(jb) + j], 0, 0, 0); \
  __builtin_amdgcn_s_setprio(0);

#define BAR_FENCE()                      \
  __builtin_amdgcn_s_barrier();          \
  asm volatile("" ::: "memory");

__global__ __launch_bounds__(512, 1) void gemm2(
    const unsigned short* __restrict__ Hb,
    const unsigned short* __restrict__ WoT,
    const float* __restrict__ b_o,
    float* __restrict__ out) {
  __shared__ unsigned short lds[65536];

  const int t = threadIdx.x;
  const int bid = blockIdx.x + (int)gridDim.x * blockIdx.y;  // 256 blocks
  const int nb = (bid & 7) * 32 + (bid >> 3);                // bijective (256%8==0)
  const int nblk = nb & 3, mblk = nb >> 2;
  const int e = mblk >> 3;
  const int m0 = mblk * 256, n0 = nblk * 256;

  const int lane = t & 63, wave = t >> 6;
  const int wr = wave >> 2, wc = wave & 3;
  const int lrow = lane & 15, khi = lane >> 4;

  const int presw = (((t & 7) ^ ((t >> 3) & 7)) << 3);
  const unsigned short* gAsrc = Hb + (size_t)(m0 + (t >> 3)) * DH + presw;
  const unsigned short* gBsrc = WoT + ((size_t)e * DM + n0 + (t >> 3)) * DH + presw;

  const int KT = DH / 64;  // 64

  auto STAGE_A = [&](int kt, int half) {
    unsigned short* d = &lds[(kt & 1) * 32768 + half * 8192 + t * 8];
    const unsigned short* s = gAsrc + (size_t)(half * 128) * DH + kt * 64;
    gload_lds16(s, d);
    gload_lds16(s + (size_t)64 * DH, d + 4096);
  };
  auto STAGE_B = [&](int kt, int half) {
    unsigned short* d = &lds[(kt & 1) * 32768 + 16384 + half * 8192 + t * 8];
    const unsigned short* s = gBsrc + (size_t)(half * 128) * DH + kt * 64;
    gload_lds16(s, d);
    gload_lds16(s + (size_t)64 * DH, d + 4096);
  };

  f32x4 acc[8][4];
#pragma unroll
  for (int m = 0; m < 8; m++)
#pragma unroll
    for (int j = 0; j < 4; j++) acc[m][j] = 0.0f;

  STAGE_A(0, 0); STAGE_A(0, 1);
  STAGE_B(0, 0); STAGE_B(0, 1);
  STAGE_B(1, 0); STAGE_B(1, 1);
  asm volatile("s_waitcnt vmcnt(4)" ::: "memory");
  BAR_FENCE();

  for (int T = 0; T < KT; ++T) {
    const int sb = (T & 1) * 32768;
    bf16x8 fa[4][2], fb01[2][2], fb23[2][2];
    // p0 (m0, j01)
    RD_A(0);
    RD_B(fb01, 0);
    if (T + 1 < KT) STAGE_A(T + 1, 0);
    __builtin_amdgcn_s_barrier();
    MFMA16(0, 0, fb01);
    BAR_FENCE();
    // p1 (m0, j23)
    RD_B(fb23, 2);
    if (T + 1 < KT) STAGE_A(T + 1, 1);
    __builtin_amdgcn_s_barrier();
    MFMA16(0, 2, fb23);
    BAR_FENCE();
    // p2 (m1, j23)
    RD_A(1);
    if (T + 2 < KT) STAGE_B(T + 2, 0);
    __builtin_amdgcn_s_barrier();
    MFMA16(4, 2, fb23);
    BAR_FENCE();
    // p3 (m1, j01)
    if (T + 2 < KT) STAGE_B(T + 2, 1);
    __builtin_amdgcn_s_barrier();
    MFMA16(4, 0, fb01);
    if (T < KT - 2)       asm volatile("s_waitcnt vmcnt(4)" ::: "memory");
    else if (T == KT - 2) asm volatile("s_waitcnt vmcnt(0)" ::: "memory");
    BAR_FENCE();
  }

  const float* bop = b_o + (size_t)e * DM;
#pragma unroll
  for (int m = 0; m < 8; m++) {
    const int rowbase = m0 + wr * 128 + (m >> 2) * 64 + (m & 3) * 16 + khi * 4;
#pragma unroll
    for (int j = 0; j < 4; j++) {
      const int gcol = n0 + wc * 64 + j * 16 + lrow;
      const float bias = bop[gcol];
#pragma unroll
      for (int r = 0; r < 4; r++)
        out[(size_t)(rowbase + r) * DM + gcol] = acc[m][j][r] + bias;
    }
  }
}

extern "C" void kernel_launch(void* const* d_in, const int* in_sizes, int n_in,
                              void* d_out, int out_size, void* d_ws, size_t ws_size,
                              hipStream_t stream) {
  const float* hs = (const float*)d_in[0];
  // d_in[1] = fwd_expert_count: equal groups of NT/EXP by construction, unused
  const float* w_gelu = (const float*)d_in[2];
  const float* w_lin = (const float*)d_in[3];
  const float* b_lin = (const float*)d_in[4];
  const float* w_o = (const float*)d_in[5];
  const float* b_o = (const float*)d_in[6];
  float* outp = (float*)d_out;

  // workspace layout (bf16 elements): Xb | WgT | WlT | WoT | Hb  (total ~352 MB)
  unsigned short* Xb = (unsigned short*)d_ws;
  unsigned short* WgT = Xb + (size_t)NT * DM;
  unsigned short* WlT = WgT + (size_t)EXP * DH * DM;
  unsigned short* WoT = WlT + (size_t)EXP * DH * DM;
  unsigned short* Hb = WoT + (size_t)EXP * DH * DM;

  cvt_bf16_k<<<dim3(2048), dim3(256), 0, stream>>>(hs, Xb, (long)NT * DM / 4);
  // Wg + Wl fused: [E][DM][DH] -> [E][DH][DM]; z = m*8 + e
  transpose_cvt64<<<dim3(DH / 64, DM / 64, 16), dim3(256), 0, stream>>>(
      w_gelu, w_lin, WgT, WlT, DM, DH);
  // Wo: [E][DH][DM] -> [E][DM][DH]
  transpose_cvt64<<<dim3(DM / 64, DH / 64, 8), dim3(256), 0, stream>>>(
      w_o, w_o, WoT, WoT, DH, DM);

  gemm1<<<dim3(DH / 128, NT / 128), dim3(256), 0, stream>>>(Xb, WgT, WlT, b_lin, Hb);
  gemm2<<<dim3(DM / 256, NT / 256), dim3(512), 0, stream>>>(Hb, WoT, b_o, outp);
}

// Round 12
// 580.912 us; speedup vs baseline: 1.0444x; 1.0444x over previous
//
#include <hip/hip_runtime.h>

#define EXP 8
#define DM 1024
#define DH 4096
#define NT 16384

typedef __attribute__((ext_vector_type(8))) short bf16x8;
typedef __attribute__((ext_vector_type(4))) float f32x4;

static __device__ __forceinline__ unsigned short f2bf(float f) {
  unsigned int u = __float_as_uint(f);
  u = u + 0x7FFFu + ((u >> 16) & 1u);
  return (unsigned short)(u >> 16);
}

static __device__ __forceinline__ void gload_lds16(const void* g, void* l) {
  __builtin_amdgcn_global_load_lds((const __attribute__((address_space(1))) void*)g,
                                   (__attribute__((address_space(3))) void*)l, 16, 0, 0);
}

// r3 swizzle: 16B-chunk index XOR (row&7), [*][64] bf16 tiles (0 conflicts)
static __device__ __forceinline__ int swz_idx(int r, int kk) {
  return r * 64 + (((kk >> 3) ^ (r & 7)) << 3);
}

// ---- X fp32 -> bf16 (same layout) ----
__global__ void cvt_bf16_k(const float* __restrict__ in, unsigned short* __restrict__ out,
                           long n4) {
  long i = (long)blockIdx.x * blockDim.x + threadIdx.x;
  const long stride = (long)gridDim.x * blockDim.x;
  for (; i < n4; i += stride) {
    const float4 v = ((const float4*)in)[i];
    ushort4 o;
    o.x = f2bf(v.x); o.y = f2bf(v.y); o.z = f2bf(v.z); o.w = f2bf(v.w);
    ((ushort4*)out)[i] = o;
  }
}

// ---- [B][K][N] fp32 -> [B][N][K] bf16, 64x64 tile, vectorized both sides ----
__global__ void transpose_cvt64(const float* __restrict__ srcA, const float* __restrict__ srcB,
                                unsigned short* __restrict__ dstA,
                                unsigned short* __restrict__ dstB, int K, int N) {
  __shared__ float tile[64][65];
  const int t = threadIdx.x;
  const int tx = t & 15, ty = t >> 4;
  const int n0 = blockIdx.x * 64, k0 = blockIdx.y * 64;
  const int z = blockIdx.z;
  const float* src = (z >> 3 ? srcB : srcA) + (size_t)(z & 7) * K * N;
  unsigned short* dst = (z >> 3 ? dstB : dstA) + (size_t)(z & 7) * K * N;
#pragma unroll
  for (int i = 0; i < 64; i += 16) {
    const float4 v = *(const float4*)&src[(size_t)(k0 + ty + i) * N + n0 + tx * 4];
    tile[ty + i][tx * 4 + 0] = v.x;
    tile[ty + i][tx * 4 + 1] = v.y;
    tile[ty + i][tx * 4 + 2] = v.z;
    tile[ty + i][tx * 4 + 3] = v.w;
  }
  __syncthreads();
#pragma unroll
  for (int i = 0; i < 64; i += 16) {
    ushort4 o;
    o.x = f2bf(tile[tx * 4 + 0][ty + i]);
    o.y = f2bf(tile[tx * 4 + 1][ty + i]);
    o.z = f2bf(tile[tx * 4 + 2][ty + i]);
    o.w = f2bf(tile[tx * 4 + 3][ty + i]);
    *(ushort4*)&dst[(size_t)(n0 + ty + i) * K + k0 + tx * 4] = o;
  }
}

// ============================================================================
// GEMM1 = round-3/round-10 exact (331 us, MfmaUtil 37, FETCH 197 MB).
// NATIVE grid order (nblk fastest): all 512 concurrent blocks work ONE
// expert -> its 16 MB of weights lives in the 32 MB aggregate L2, fetched
// ~once.  XCD-chunked remap (r11) serialized one expert per XCD -> 16 MB
// >> 4 MB per-XCD L2 -> FETCH x4.4, dur +18 us.  DO NOT remap this kernel.
// ============================================================================
__global__ __launch_bounds__(256, 2) void gemm1(
    const unsigned short* __restrict__ Xb,
    const unsigned short* __restrict__ WgT,
    const unsigned short* __restrict__ WlT,
    const float* __restrict__ b_lin,
    unsigned short* __restrict__ Hb) {
  __shared__ unsigned short sA[128 * 64];
  __shared__ unsigned short sBg[128 * 64];
  __shared__ unsigned short sBl[128 * 64];

  const int t = threadIdx.x;
  const int nblk = blockIdx.x, mblk = blockIdx.y;
  const int e = mblk >> 4;
  const int m0 = mblk * 128, n0 = nblk * 128;

  const int lane = t & 63;
  const int wave = t >> 6;
  const int wr = wave >> 1, wc = wave & 1;
  const int lrow = lane & 15;
  const int lk8 = (lane >> 4) * 8;

  const int srow = t >> 3;
  const int schunk = t & 7;
  const int ssw = ((schunk ^ (srow & 7)) << 3);

  const unsigned short* gA = Xb + (size_t)m0 * DM + ssw;
  const unsigned short* gG = WgT + (size_t)e * DH * DM + (size_t)n0 * DM + ssw;
  const unsigned short* gL = WlT + (size_t)e * DH * DM + (size_t)n0 * DM + ssw;

  f32x4 accg[4][4], accl[4][4];
#pragma unroll
  for (int i = 0; i < 4; i++)
#pragma unroll
    for (int j = 0; j < 4; j++) { accg[i][j] = 0.0f; accl[i][j] = 0.0f; }

  for (int kt = 0; kt < DM / 64; ++kt) {
    const int k0 = kt * 64;
#pragma unroll
    for (int c = 0; c < 4; c++) {
      const int row = c * 32 + srow;
      gload_lds16(gA + (size_t)row * DM + k0, (char*)sA + row * 128 + schunk * 16);
      gload_lds16(gG + (size_t)row * DM + k0, (char*)sBg + row * 128 + schunk * 16);
      gload_lds16(gL + (size_t)row * DM + k0, (char*)sBl + row * 128 + schunk * 16);
    }
    __syncthreads();
#pragma unroll
    for (int ks = 0; ks < 2; ks++) {
      const int kk = ks * 32 + lk8;
      bf16x8 af[4], bg[4], bl[4];
#pragma unroll
      for (int i = 0; i < 4; i++)
        af[i] = *(const bf16x8*)&sA[swz_idx(wr * 64 + i * 16 + lrow, kk)];
#pragma unroll
      for (int j = 0; j < 4; j++) {
        bg[j] = *(const bf16x8*)&sBg[swz_idx(wc * 64 + j * 16 + lrow, kk)];
        bl[j] = *(const bf16x8*)&sBl[swz_idx(wc * 64 + j * 16 + lrow, kk)];
      }
#pragma unroll
      for (int i = 0; i < 4; i++)
#pragma unroll
        for (int j = 0; j < 4; j++) {
          accg[i][j] = __builtin_amdgcn_mfma_f32_16x16x32_bf16(af[i], bg[j], accg[i][j], 0, 0, 0);
          accl[i][j] = __builtin_amdgcn_mfma_f32_16x16x32_bf16(af[i], bl[j], accl[i][j], 0, 0, 0);
        }
    }
    __syncthreads();
  }

  const float* bl_p = b_lin + (size_t)e * DH;
  const int r0 = (lane >> 4) * 4;
#pragma unroll
  for (int i = 0; i < 4; i++) {
    const int grow = m0 + wr * 64 + i * 16 + r0;
#pragma unroll
    for (int j = 0; j < 4; j++) {
      const int gcol = n0 + wc * 64 + j * 16 + lrow;
      const float bias = bl_p[gcol];
#pragma unroll
      for (int r = 0; r < 4; r++) {
        const float g = accg[i][j][r];
        const float li = accl[i][j][r] + bias;
        const float u = 0.7978845608028654f * (g + 0.044715f * g * g * g);
        const float th = 1.0f - 2.0f / (1.0f + __expf(2.0f * u));
        const float h = 0.5f * g * (1.0f + th) * li;
        Hb[(size_t)(grow + r) * DH + gcol] = f2bf(h);
      }
    }
  }
}

// ============================================================================
// GEMM2 = round-9/round-10 exact 8-phase (measured ~120 us).  Native order.
// ============================================================================

#define LDSA(row, chunk) lds[sb + (row) * 64 + ((((chunk) ^ ((row) & 7))) << 3)]
#define LDSB(row, chunk) lds[sb + 16384 + (row) * 64 + ((((chunk) ^ ((row) & 7))) << 3)]

#define RD_A(mh)                                                                   \
  _Pragma("unroll") for (int i = 0; i < 4; i++) _Pragma("unroll") for (int ks = 0; \
                                                                       ks < 2;    \
                                                                       ks++)      \
      fa[i][ks] = *(const bf16x8*)&LDSA(wr * 128 + (mh) * 64 + i * 16 + lrow, ks * 4 + khi);

#define RD_B(dst, jb)                                                              \
  _Pragma("unroll") for (int j = 0; j < 2; j++) _Pragma("unroll") for (int ks = 0; \
                                                                       ks < 2;    \
                                                                       ks++)      \
      dst[j][ks] = *(const bf16x8*)&LDSB(wc * 64 + ((jb) + j) * 16 + lrow, ks * 4 + khi);

#define MFMA16(mi, jb, fb)                                                        \
  __builtin_amdgcn_s_setprio(1);                                                  \
  _Pragma("unroll") for (int i = 0; i < 4; i++) _Pragma("unroll") for (int j = 0; \
                                                                       j < 2;    \
                                                                       j++)      \
      _Pragma("unroll") for (int ks = 0; ks < 2; ks++) acc[(mi) + i][(jb) + j] =  \
          __builtin_amdgcn_mfma_f32_16x16x32_bf16(fa[i][ks], fb[j][ks],           \
                                                  acc[(mi) + i][(jb) + j], 0, 0, 0); \
  __builtin_amdgcn_s_setprio(0);

#define BAR_FENCE()                      \
  __builtin_amdgcn_s_barrier();          \
  asm volatile("" ::: "memory");

__global__ __launch_bounds__(512, 1) void gemm2(
    const unsigned short* __restrict__ Hb,
    const unsigned short* __restrict__ WoT,
    const float* __restrict__ b_o,
    float* __restrict__ out) {
  __shared__ unsigned short lds[65536];

  const int t = threadIdx.x;
  const int nblk = blockIdx.x, mblk = blockIdx.y;
  const int e = mblk >> 3;
  const int m0 = mblk * 256, n0 = nblk * 256;

  const int lane = t & 63, wave = t >> 6;
  const int wr = wave >> 2, wc = wave & 3;
  const int lrow = lane & 15, khi = lane >> 4;

  const int presw = (((t & 7) ^ ((t >> 3) & 7)) << 3);
  const unsigned short* gAsrc = Hb + (size_t)(m0 + (t >> 3)) * DH + presw;
  const unsigned short* gBsrc = WoT + ((size_t)e * DM + n0 + (t >> 3)) * DH + presw;

  const int KT = DH / 64;  // 64

  auto STAGE_A = [&](int kt, int half) {
    unsigned short* d = &lds[(kt & 1) * 32768 + half * 8192 + t * 8];
    const unsigned short* s = gAsrc + (size_t)(half * 128) * DH + kt * 64;
    gload_lds16(s, d);
    gload_lds16(s + (size_t)64 * DH, d + 4096);
  };
  auto STAGE_B = [&](int kt, int half) {
    unsigned short* d = &lds[(kt & 1) * 32768 + 16384 + half * 8192 + t * 8];
    const unsigned short* s = gBsrc + (size_t)(half * 128) * DH + kt * 64;
    gload_lds16(s, d);
    gload_lds16(s + (size_t)64 * DH, d + 4096);
  };

  f32x4 acc[8][4];
#pragma unroll
  for (int m = 0; m < 8; m++)
#pragma unroll
    for (int j = 0; j < 4; j++) acc[m][j] = 0.0f;

  STAGE_A(0, 0); STAGE_A(0, 1);
  STAGE_B(0, 0); STAGE_B(0, 1);
  STAGE_B(1, 0); STAGE_B(1, 1);
  asm volatile("s_waitcnt vmcnt(4)" ::: "memory");
  BAR_FENCE();

  for (int T = 0; T < KT; ++T) {
    const int sb = (T & 1) * 32768;
    bf16x8 fa[4][2], fb01[2][2], fb23[2][2];
    // p0 (m0, j01)
    RD_A(0);
    RD_B(fb01, 0);
    if (T + 1 < KT) STAGE_A(T + 1, 0);
    __builtin_amdgcn_s_barrier();
    MFMA16(0, 0, fb01);
    BAR_FENCE();
    // p1 (m0, j23)
    RD_B(fb23, 2);
    if (T + 1 < KT) STAGE_A(T + 1, 1);
    __builtin_amdgcn_s_barrier();
    MFMA16(0, 2, fb23);
    BAR_FENCE();
    // p2 (m1, j23)
    RD_A(1);
    if (T + 2 < KT) STAGE_B(T + 2, 0);
    __builtin_amdgcn_s_barrier();
    MFMA16(4, 2, fb23);
    BAR_FENCE();
    // p3 (m1, j01)
    if (T + 2 < KT) STAGE_B(T + 2, 1);
    __builtin_amdgcn_s_barrier();
    MFMA16(4, 0, fb01);
    if (T < KT - 2)       asm volatile("s_waitcnt vmcnt(4)" ::: "memory");
    else if (T == KT - 2) asm volatile("s_waitcnt vmcnt(0)" ::: "memory");
    BAR_FENCE();
  }

  const float* bop = b_o + (size_t)e * DM;
#pragma unroll
  for (int m = 0; m < 8; m++) {
    const int rowbase = m0 + wr * 128 + (m >> 2) * 64 + (m & 3) * 16 + khi * 4;
#pragma unroll
    for (int j = 0; j < 4; j++) {
      const int gcol = n0 + wc * 64 + j * 16 + lrow;
      const float bias = bop[gcol];
#pragma unroll
      for (int r = 0; r < 4; r++)
        out[(size_t)(rowbase + r) * DM + gcol] = acc[m][j][r] + bias;
    }
  }
}

extern "C" void kernel_launch(void* const* d_in, const int* in_sizes, int n_in,
                              void* d_out, int out_size, void* d_ws, size_t ws_size,
                              hipStream_t stream) {
  const float* hs = (const float*)d_in[0];
  // d_in[1] = fwd_expert_count: equal groups of NT/EXP by construction, unused
  const float* w_gelu = (const float*)d_in[2];
  const float* w_lin = (const float*)d_in[3];
  const float* b_lin = (const float*)d_in[4];
  const float* w_o = (const float*)d_in[5];
  const float* b_o = (const float*)d_in[6];
  float* outp = (float*)d_out;

  // workspace layout (bf16 elements): Xb | WgT | WlT | WoT | Hb  (total ~352 MB)
  unsigned short* Xb = (unsigned short*)d_ws;
  unsigned short* WgT = Xb + (size_t)NT * DM;
  unsigned short* WlT = WgT + (size_t)EXP * DH * DM;
  unsigned short* WoT = WlT + (size_t)EXP * DH * DM;
  unsigned short* Hb = WoT + (size_t)EXP * DH * DM;

  cvt_bf16_k<<<dim3(2048), dim3(256), 0, stream>>>(hs, Xb, (long)NT * DM / 4);
  // Wg + Wl fused: [E][DM][DH] -> [E][DH][DM]; z = m*8 + e
  transpose_cvt64<<<dim3(DH / 64, DM / 64, 16), dim3(256), 0, stream>>>(
      w_gelu, w_lin, WgT, WlT, DM, DH);
  // Wo: [E][DH][DM] -> [E][DM][DH]
  transpose_cvt64<<<dim3(DM / 64, DH / 64, 8), dim3(256), 0, stream>>>(
      w_o, w_o, WoT, WoT, DH, DM);

  gemm1<<<dim3(DH / 128, NT / 128), dim3(256), 0, stream>>>(Xb, WgT, WlT, b_lin, Hb);
  gemm2<<<dim3(DM / 256, NT / 256), dim3(512), 0, stream>>>(Hb, WoT, b_o, outp);
}

// Round 13
// 557.777 us; speedup vs baseline: 1.0877x; 1.0415x over previous
//
#include <hip/hip_runtime.h>

#define EXP 8
#define DM 1024
#define DH 4096
#define NT 16384

typedef __attribute__((ext_vector_type(8))) short bf16x8;
typedef __attribute__((ext_vector_type(4))) float f32x4;

static __device__ __forceinline__ unsigned short f2bf(float f) {
  unsigned int u = __float_as_uint(f);
  u = u + 0x7FFFu + ((u >> 16) & 1u);
  return (unsigned short)(u >> 16);
}

static __device__ __forceinline__ void gload_lds16(const void* g, void* l) {
  __builtin_amdgcn_global_load_lds((const __attribute__((address_space(1))) void*)g,
                                   (__attribute__((address_space(3))) void*)l, 16, 0, 0);
}

// ---- X fp32 -> bf16 (same layout) ----
__global__ void cvt_bf16_k(const float* __restrict__ in, unsigned short* __restrict__ out,
                           long n4) {
  long i = (long)blockIdx.x * blockDim.x + threadIdx.x;
  const long stride = (long)gridDim.x * blockDim.x;
  for (; i < n4; i += stride) {
    const float4 v = ((const float4*)in)[i];
    ushort4 o;
    o.x = f2bf(v.x); o.y = f2bf(v.y); o.z = f2bf(v.z); o.w = f2bf(v.w);
    ((ushort4*)out)[i] = o;
  }
}

// ---- generic [B][K][N] fp32 -> [B][N][K] bf16, 64x64 vectorized (for Wo) ----
__global__ void transpose_cvt64(const float* __restrict__ src0,
                                unsigned short* __restrict__ dst0, int K, int N) {
  __shared__ float tile[64][65];
  const int t = threadIdx.x;
  const int tx = t & 15, ty = t >> 4;
  const int n0 = blockIdx.x * 64, k0 = blockIdx.y * 64;
  const int z = blockIdx.z;
  const float* src = src0 + (size_t)z * K * N;
  unsigned short* dst = dst0 + (size_t)z * K * N;
#pragma unroll
  for (int i = 0; i < 64; i += 16) {
    const float4 v = *(const float4*)&src[(size_t)(k0 + ty + i) * N + n0 + tx * 4];
    tile[ty + i][tx * 4 + 0] = v.x;
    tile[ty + i][tx * 4 + 1] = v.y;
    tile[ty + i][tx * 4 + 2] = v.z;
    tile[ty + i][tx * 4 + 3] = v.w;
  }
  __syncthreads();
#pragma unroll
  for (int i = 0; i < 64; i += 16) {
    ushort4 o;
    o.x = f2bf(tile[tx * 4 + 0][ty + i]);
    o.y = f2bf(tile[tx * 4 + 1][ty + i]);
    o.z = f2bf(tile[tx * 4 + 2][ty + i]);
    o.w = f2bf(tile[tx * 4 + 3][ty + i]);
    *(ushort4*)&dst[(size_t)(n0 + ty + i) * K + k0 + tx * 4] = o;
  }
}

// ---- Wg+Wl -> W1T[E][2*DH][DM], fragment-interleaved ----
// hidden col n -> panel row ((n>>4)<<5) + (n&15) + (gate?0:16).
// Rows 32h..32h+16 = gate cols 16h.., rows 32h+16..32h+32 = linear same cols,
// so a 16-row MFMA B-fragment is pure gate or pure linear of one col-16-group:
// acc fragment pairs (2p,2p+1) = (gate,linear) of the SAME (rows, cols) ->
// gelu fusion is in-register, no 3rd LDS buffer, no exchange epilogue.
__global__ void transpose_cvt64_il(const float* __restrict__ w_gelu,
                                   const float* __restrict__ w_lin,
                                   unsigned short* __restrict__ W1T) {
  __shared__ float tile[64][65];
  const int t = threadIdx.x;
  const int tx = t & 15, ty = t >> 4;
  const int n0 = blockIdx.x * 64, k0 = blockIdx.y * 64;
  const int z = blockIdx.z;             // z<8: gate expert z; z>=8: linear expert z-8
  const int gl16 = (z >> 3) * 16;
  const float* src = (z >> 3 ? w_lin : w_gelu) + (size_t)(z & 7) * DM * DH;
  unsigned short* dst = W1T + (size_t)(z & 7) * 2 * DH * DM;
#pragma unroll
  for (int i = 0; i < 64; i += 16) {
    const float4 v = *(const float4*)&src[(size_t)(k0 + ty + i) * DH + n0 + tx * 4];
    tile[ty + i][tx * 4 + 0] = v.x;
    tile[ty + i][tx * 4 + 1] = v.y;
    tile[ty + i][tx * 4 + 2] = v.z;
    tile[ty + i][tx * 4 + 3] = v.w;
  }
  __syncthreads();
#pragma unroll
  for (int i = 0; i < 64; i += 16) {
    const int n = n0 + ty + i;
    const int rowI = ((n >> 4) << 5) + (n & 15) + gl16;
    ushort4 o;
    o.x = f2bf(tile[tx * 4 + 0][ty + i]);
    o.y = f2bf(tile[tx * 4 + 1][ty + i]);
    o.z = f2bf(tile[tx * 4 + 2][ty + i]);
    o.w = f2bf(tile[tx * 4 + 3][ty + i]);
    *(ushort4*)&dst[(size_t)rowI * DM + k0 + tx * 4] = o;
  }
}

// ============================================================================
// Shared 8-phase machinery (round-9/10 proven; gemm2 measured ~120us/46%).
// ============================================================================

#define LDSA(row, chunk) lds[sb + (row) * 64 + ((((chunk) ^ ((row) & 7))) << 3)]
#define LDSB(row, chunk) lds[sb + 16384 + (row) * 64 + ((((chunk) ^ ((row) & 7))) << 3)]

#define RD_A(mh)                                                                   \
  _Pragma("unroll") for (int i = 0; i < 4; i++) _Pragma("unroll") for (int ks = 0; \
                                                                       ks < 2;    \
                                                                       ks++)      \
      fa[i][ks] = *(const bf16x8*)&LDSA(wr * 128 + (mh) * 64 + i * 16 + lrow, ks * 4 + khi);

#define RD_B(dst, jb)                                                              \
  _Pragma("unroll") for (int j = 0; j < 2; j++) _Pragma("unroll") for (int ks = 0; \
                                                                       ks < 2;    \
                                                                       ks++)      \
      dst[j][ks] = *(const bf16x8*)&LDSB(wc * 64 + ((jb) + j) * 16 + lrow, ks * 4 + khi);

#define MFMA16(mi, jb, fb)                                                        \
  __builtin_amdgcn_s_setprio(1);                                                  \
  _Pragma("unroll") for (int i = 0; i < 4; i++) _Pragma("unroll") for (int j = 0; \
                                                                       j < 2;    \
                                                                       j++)      \
      _Pragma("unroll") for (int ks = 0; ks < 2; ks++) acc[(mi) + i][(jb) + j] =  \
          __builtin_amdgcn_mfma_f32_16x16x32_bf16(fa[i][ks], fb[j][ks],           \
                                                  acc[(mi) + i][(jb) + j], 0, 0, 0); \
  __builtin_amdgcn_s_setprio(0);

#define BAR_FENCE()                      \
  __builtin_amdgcn_s_barrier();          \
  asm volatile("" ::: "memory");

// 8-phase K-loop body: A panel stride SA, B panel stride SB (both k-contig).
#define PIPE_LOOP(KT)                                                   \
  STAGE_A(0, 0); STAGE_A(0, 1);                                         \
  STAGE_B(0, 0); STAGE_B(0, 1);                                         \
  STAGE_B(1, 0); STAGE_B(1, 1);                                         \
  asm volatile("s_waitcnt vmcnt(4)" ::: "memory");                      \
  BAR_FENCE();                                                          \
  for (int T = 0; T < (KT); ++T) {                                      \
    const int sb = (T & 1) * 32768;                                     \
    bf16x8 fa[4][2], fb01[2][2], fb23[2][2];                            \
    RD_A(0);                                                            \
    RD_B(fb01, 0);                                                      \
    if (T + 1 < (KT)) STAGE_A(T + 1, 0);                                \
    __builtin_amdgcn_s_barrier();                                       \
    MFMA16(0, 0, fb01);                                                 \
    BAR_FENCE();                                                        \
    RD_B(fb23, 2);                                                      \
    if (T + 1 < (KT)) STAGE_A(T + 1, 1);                                \
    __builtin_amdgcn_s_barrier();                                       \
    MFMA16(0, 2, fb23);                                                 \
    BAR_FENCE();                                                        \
    RD_A(1);                                                            \
    if (T + 2 < (KT)) STAGE_B(T + 2, 0);                                \
    __builtin_amdgcn_s_barrier();                                       \
    MFMA16(4, 2, fb23);                                                 \
    BAR_FENCE();                                                        \
    if (T + 2 < (KT)) STAGE_B(T + 2, 1);                                \
    __builtin_amdgcn_s_barrier();                                       \
    MFMA16(4, 0, fb01);                                                 \
    if (T < (KT)-2)        asm volatile("s_waitcnt vmcnt(4)" ::: "memory"); \
    else if (T == (KT)-2)  asm volatile("s_waitcnt vmcnt(0)" ::: "memory"); \
    BAR_FENCE();                                                        \
  }

// ============================================================================
// GEMM1: 8-phase on interleaved W1T.  256(tok) x 256(panel rows = 128 hidden
// cols, gate+linear) tile, BK=64, KT=16.  Epilogue fully in-register.
// ============================================================================
__global__ __launch_bounds__(512, 1) void gemm1(
    const unsigned short* __restrict__ Xb,
    const unsigned short* __restrict__ W1T,
    const float* __restrict__ b_lin,
    unsigned short* __restrict__ Hb) {
  __shared__ unsigned short lds[65536];

  const int t = threadIdx.x;
  const int nblk = blockIdx.x, mblk = blockIdx.y;  // native order (r11 lesson)
  const int e = mblk >> 3;
  const int m0 = mblk * 256, n0 = nblk * 256;

  const int lane = t & 63, wave = t >> 6;
  const int wr = wave >> 2, wc = wave & 3;
  const int lrow = lane & 15, khi = lane >> 4;

  const int presw = (((t & 7) ^ ((t >> 3) & 7)) << 3);
  const unsigned short* gAsrc = Xb + (size_t)(m0 + (t >> 3)) * DM + presw;
  const unsigned short* gBsrc = W1T + ((size_t)e * 2 * DH + n0 + (t >> 3)) * DM + presw;

  auto STAGE_A = [&](int kt, int half) {
    unsigned short* d = &lds[(kt & 1) * 32768 + half * 8192 + t * 8];
    const unsigned short* s = gAsrc + (size_t)(half * 128) * DM + kt * 64;
    gload_lds16(s, d);
    gload_lds16(s + (size_t)64 * DM, d + 4096);
  };
  auto STAGE_B = [&](int kt, int half) {
    unsigned short* d = &lds[(kt & 1) * 32768 + 16384 + half * 8192 + t * 8];
    const unsigned short* s = gBsrc + (size_t)(half * 128) * DM + kt * 64;
    gload_lds16(s, d);
    gload_lds16(s + (size_t)64 * DM, d + 4096);
  };

  f32x4 acc[8][4];
#pragma unroll
  for (int m = 0; m < 8; m++)
#pragma unroll
    for (int j = 0; j < 4; j++) acc[m][j] = 0.0f;

  PIPE_LOOP(DM / 64);

  // epilogue: pair p -> (gate=acc[m][2p], linear=acc[m][2p+1]) of hidden col
  // hcol = nblk*128 + (2*wc+p)*16 + lrow
#pragma unroll
  for (int m = 0; m < 8; m++) {
    const int rowbase = m0 + wr * 128 + (m >> 2) * 64 + (m & 3) * 16 + khi * 4;
#pragma unroll
    for (int p = 0; p < 2; p++) {
      const int hcol = nblk * 128 + (2 * wc + p) * 16 + lrow;
      const float bias = b_lin[(size_t)e * DH + hcol];
#pragma unroll
      for (int r = 0; r < 4; r++) {
        const float g = acc[m][2 * p][r];
        const float li = acc[m][2 * p + 1][r] + bias;
        const float u = 0.7978845608028654f * (g + 0.044715f * g * g * g);
        const float th = 1.0f - 2.0f / (1.0f + __expf(2.0f * u));
        const float h = 0.5f * g * (1.0f + th) * li;
        Hb[(size_t)(rowbase + r) * DH + hcol] = f2bf(h);
      }
    }
  }
}

// ============================================================================
// GEMM2 = round-9/10/12 exact 8-phase (measured ~120 us).  Native order.
// ============================================================================
__global__ __launch_bounds__(512, 1) void gemm2(
    const unsigned short* __restrict__ Hb,
    const unsigned short* __restrict__ WoT,
    const float* __restrict__ b_o,
    float* __restrict__ out) {
  __shared__ unsigned short lds[65536];

  const int t = threadIdx.x;
  const int nblk = blockIdx.x, mblk = blockIdx.y;
  const int e = mblk >> 3;
  const int m0 = mblk * 256, n0 = nblk * 256;

  const int lane = t & 63, wave = t >> 6;
  const int wr = wave >> 2, wc = wave & 3;
  const int lrow = lane & 15, khi = lane >> 4;

  const int presw = (((t & 7) ^ ((t >> 3) & 7)) << 3);
  const unsigned short* gAsrc = Hb + (size_t)(m0 + (t >> 3)) * DH + presw;
  const unsigned short* gBsrc = WoT + ((size_t)e * DM + n0 + (t >> 3)) * DH + presw;

  auto STAGE_A = [&](int kt, int half) {
    unsigned short* d = &lds[(kt & 1) * 32768 + half * 8192 + t * 8];
    const unsigned short* s = gAsrc + (size_t)(half * 128) * DH + kt * 64;
    gload_lds16(s, d);
    gload_lds16(s + (size_t)64 * DH, d + 4096);
  };
  auto STAGE_B = [&](int kt, int half) {
    unsigned short* d = &lds[(kt & 1) * 32768 + 16384 + half * 8192 + t * 8];
    const unsigned short* s = gBsrc + (size_t)(half * 128) * DH + kt * 64;
    gload_lds16(s, d);
    gload_lds16(s + (size_t)64 * DH, d + 4096);
  };

  f32x4 acc[8][4];
#pragma unroll
  for (int m = 0; m < 8; m++)
#pragma unroll
    for (int j = 0; j < 4; j++) acc[m][j] = 0.0f;

  PIPE_LOOP(DH / 64);

  const float* bop = b_o + (size_t)e * DM;
#pragma unroll
  for (int m = 0; m < 8; m++) {
    const int rowbase = m0 + wr * 128 + (m >> 2) * 64 + (m & 3) * 16 + khi * 4;
#pragma unroll
    for (int j = 0; j < 4; j++) {
      const int gcol = n0 + wc * 64 + j * 16 + lrow;
      const float bias = bop[gcol];
#pragma unroll
      for (int r = 0; r < 4; r++)
        out[(size_t)(rowbase + r) * DM + gcol] = acc[m][j][r] + bias;
    }
  }
}

extern "C" void kernel_launch(void* const* d_in, const int* in_sizes, int n_in,
                              void* d_out, int out_size, void* d_ws, size_t ws_size,
                              hipStream_t stream) {
  const float* hs = (const float*)d_in[0];
  // d_in[1] = fwd_expert_count: equal groups of NT/EXP by construction, unused
  const float* w_gelu = (const float*)d_in[2];
  const float* w_lin = (const float*)d_in[3];
  const float* b_lin = (const float*)d_in[4];
  const float* w_o = (const float*)d_in[5];
  const float* b_o = (const float*)d_in[6];
  float* outp = (float*)d_out;

  // workspace (bf16 elements): Xb | W1T (E*2*DH*DM) | WoT | Hb
  unsigned short* Xb = (unsigned short*)d_ws;
  unsigned short* W1T = Xb + (size_t)NT * DM;
  unsigned short* WoT = W1T + (size_t)EXP * 2 * DH * DM;
  unsigned short* Hb = WoT + (size_t)EXP * DH * DM;

  cvt_bf16_k<<<dim3(2048), dim3(256), 0, stream>>>(hs, Xb, (long)NT * DM / 4);
  // Wg+Wl -> fragment-interleaved W1T
  transpose_cvt64_il<<<dim3(DH / 64, DM / 64, 16), dim3(256), 0, stream>>>(
      w_gelu, w_lin, W1T);
  // Wo: [E][DH][DM] -> [E][DM][DH]
  transpose_cvt64<<<dim3(DM / 64, DH / 64, 8), dim3(256), 0, stream>>>(w_o, WoT, DH, DM);

  gemm1<<<dim3(2 * DH / 256, NT / 256), dim3(512), 0, stream>>>(Xb, W1T, b_lin, Hb);
  gemm2<<<dim3(DM / 256, NT / 256), dim3(512), 0, stream>>>(Hb, WoT, b_o, outp);
}